// Round 6
// baseline (138.091 us; speedup 1.0000x reference)
//
#include <hip/hip_runtime.h>
#include <cstdint>
#include <cstddef>

#define LRALPHA 0.1f
static constexpr int NR = 8192;      // N and Na
static constexpr int EF = 256;
static constexpr int IN_F = 512;
static constexpr int OUT_F = 512;
static constexpr int KP = 1536;      // split-bf16 augmented K (hi,hi,lo)
static constexpr int NCH = 128;      // chunks for column scans
static constexpr int CHR = 64;       // rows per chunk (NCH*CHR = 8192)
static constexpr int KITERS = KP / 32;  // 48

typedef __attribute__((ext_vector_type(8))) short bf16x8;
typedef __attribute__((ext_vector_type(4))) float f32x4;

__device__ __forceinline__ unsigned short f2bf(float x) {
  unsigned int u = __builtin_bit_cast(unsigned int, x);
  u += 0x7fffu + ((u >> 16) & 1u);
  return (unsigned short)(u >> 16);
}
__device__ __forceinline__ float bf2f(unsigned short h) {
  unsigned int u = ((unsigned int)h) << 16;
  return __builtin_bit_cast(float, u);
}

// ---- fused s1/s2: one wave per row over 16384 virtual rows ----
__global__ __launch_bounds__(256) void k_dots2(const float* __restrict__ feat_edge,
                                               const float* __restrict__ feat_edge_a,
                                               const float* __restrict__ att,
                                               float* __restrict__ s1,
                                               float* __restrict__ s2) {
  int vrow = blockIdx.x * 4 + (threadIdx.x >> 6);
  int lane = threadIdx.x & 63;
  const float* feat; const float* av; float* outp; int row;
  if (vrow < NR) { row = vrow; feat = feat_edge; av = att; outp = s1; }
  else { row = vrow - NR; feat = feat_edge_a; av = att + EF; outp = s2; }
  float4 f = reinterpret_cast<const float4*>(feat + (size_t)row * EF)[lane];
  float4 a = reinterpret_cast<const float4*>(av)[lane];
  float d = f.x * a.x + f.y * a.y + f.z * a.z + f.w * a.w;
#pragma unroll
  for (int off = 32; off > 0; off >>= 1) d += __shfl_xor(d, off);
  if (lane == 0) outp[row] = d;
}

// ---- pack weight TRANSPOSED into split-bf16 [hi | lo | hi], B3t[n][k'] ----
__global__ __launch_bounds__(256) void k_packB(const float* __restrict__ W, short* __restrict__ B3t) {
  int i = blockIdx.x * 256 + threadIdx.x;  // < 512*512
  int n = i >> 9, k = i & 511;
  float x = W[(size_t)k * OUT_F + n];
  unsigned short h = f2bf(x);
  unsigned short l = f2bf(x - bf2f(h));
  short* base = B3t + (size_t)n * KP;
  base[k] = (short)h;
  base[512 + k] = (short)l;
  base[1024 + k] = (short)h;
}

// ---- Wh = split3(A) @ B3t^T : 128x128 tile, BK=32, reg-staged 3-deep ring ----
// A is packed to [hi|hi|lo] ON THE FLY in registers (k>=1024 -> lo part).
// Barrier is RAW s_barrier + lgkmcnt(0) only — no vmcnt drain, so the
// compiler's precise register-dep vmcnt waits keep ~3 iterations of global
// loads in flight across barriers (the thing __syncthreads forbids).
struct SReg { float4 a0, a1, a2, a3; int4 b0, b1; };

__global__ __launch_bounds__(256) void k_gemm(const float* __restrict__ A,
                                              const short* __restrict__ B3t,
                                              float* __restrict__ Wh) {
  // per buffer: [slot=k/8 (4)][row (128)][8 bf16] = 4096 shorts, conflict-free ds_read_b128
  __shared__ short lA[3][4096];
  __shared__ short lB[3][4096];
  const int tid = threadIdx.x;
  const int wid = tid >> 6, lane = tid & 63;
  const int wr = wid >> 1, wc = wid & 1;
  const int m0 = blockIdx.x * 128, n0 = blockIdx.y * 128;
  const int slot = lane >> 4, fr = lane & 15;

  // staging map: waves 0-1 -> k-half 0, waves 2-3 -> k-half 1; row = tid&127.
  // 8-lane groups write 128 contiguous bytes -> zero bank conflicts
  // (R5's sj=tid&1 map cost exactly 8 extra cyc per ds_write_b128).
  const int srow = tid & 127, sj = tid >> 7;
  const float* gA = A + (size_t)(m0 + srow) * IN_F + sj * 16;
  const short* gB = B3t + (size_t)(n0 + srow) * KP + sj * 16;
  const int wOff0 = (2 * sj) * 1024 + srow * 8;   // shorts; cell (slot=2sj, srow)
  const int wOff1 = wOff0 + 1024;                 // cell (slot=2sj+1, srow)

  f32x4 acc[4][4] = {};

  auto loadR = [&](SReg& s, int t) {
    int kb = t * 32;
    const float* pa = gA + (kb & 511);
    s.a0 = *reinterpret_cast<const float4*>(pa);
    s.a1 = *reinterpret_cast<const float4*>(pa + 4);
    s.a2 = *reinterpret_cast<const float4*>(pa + 8);
    s.a3 = *reinterpret_cast<const float4*>(pa + 12);
    s.b0 = *reinterpret_cast<const int4*>(gB + kb);
    s.b1 = *reinterpret_cast<const int4*>(gB + kb + 8);
  };

  auto cvt8 = [&](float4 p, float4 q, bool uselo) -> int4 {
    float xs[8] = {p.x, p.y, p.z, p.w, q.x, q.y, q.z, q.w};
    bf16x8 r;
#pragma unroll
    for (int e = 0; e < 8; ++e) {
      unsigned short hh = f2bf(xs[e]);
      if (uselo) hh = f2bf(xs[e] - bf2f(hh));
      r[e] = (short)hh;
    }
    return __builtin_bit_cast(int4, r);
  };

  auto writeL = [&](int buf, SReg& s, int t) {
    bool uselo = (t >= 32);                        // third K-segment: lo(A)
    int4 c0 = cvt8(s.a0, s.a1, uselo);
    int4 c1 = cvt8(s.a2, s.a3, uselo);
    *reinterpret_cast<int4*>(&lA[buf][wOff0]) = c0;
    *reinterpret_cast<int4*>(&lA[buf][wOff1]) = c1;
    *reinterpret_cast<int4*>(&lB[buf][wOff0]) = s.b0;
    *reinterpret_cast<int4*>(&lB[buf][wOff1]) = s.b1;
  };

  auto compute = [&](int buf) {
    bf16x8 af[4], bv[4];
#pragma unroll
    for (int m = 0; m < 4; ++m)
      af[m] = *reinterpret_cast<const bf16x8*>(&lA[buf][slot * 1024 + (wr * 64 + m * 16 + fr) * 8]);
#pragma unroll
    for (int n = 0; n < 4; ++n)
      bv[n] = *reinterpret_cast<const bf16x8*>(&lB[buf][slot * 1024 + (wc * 64 + n * 16 + fr) * 8]);
#pragma unroll
    for (int m = 0; m < 4; ++m)
#pragma unroll
      for (int n = 0; n < 4; ++n)
        acc[m][n] = __builtin_amdgcn_mfma_f32_16x16x32_bf16(af[m], bv[n], acc[m][n], 0, 0, 0);
  };

  // lgkmcnt(0): my ds_writes visible + my ds_reads done; NO vmcnt drain.
#define BAR()                                               \
  do {                                                      \
    asm volatile("s_waitcnt lgkmcnt(0)" ::: "memory");      \
    __builtin_amdgcn_s_barrier();                           \
  } while (0)

  SReg S0, S1, S2;
  loadR(S0, 0); loadR(S1, 1); loadR(S2, 2);
  writeL(0, S0, 0);
  loadR(S0, 3);      // refill S0 with tile 3
  BAR();

#define STEP(T, SNXT, BUFC, BUFN)                      \
  {                                                    \
    int t_ = (T);                                      \
    if (t_ + 1 < KITERS) writeL(BUFN, SNXT, t_ + 1);   \
    if (t_ + 4 < KITERS) loadR(SNXT, t_ + 4);          \
    compute(BUFC);                                     \
    BAR();                                             \
  }

  for (int t = 0; t < KITERS; t += 3) {
    STEP(t + 0, S1, 0, 1);
    STEP(t + 1, S2, 1, 2);
    STEP(t + 2, S0, 2, 0);
  }
#undef STEP
#undef BAR

#pragma unroll
  for (int m = 0; m < 4; ++m) {
#pragma unroll
    for (int n = 0; n < 4; ++n) {
      int row = m0 + wr * 64 + m * 16 + slot * 4;  // C/D: row=(lane>>4)*4+reg
      int col = n0 + wc * 64 + n * 16 + fr;        //      col=lane&15
#pragma unroll
      for (int r = 0; r < 4; ++r)
        Wh[(size_t)(row + r) * OUT_F + col] = acc[m][n][r];
    }
  }
}

// ---- rank-by-counting: 8 lanes per key, L2-resident reads ----
__global__ __launch_bounds__(256) void k_rank(const float* __restrict__ s2,
                                              float* __restrict__ s2s, int* __restrict__ perm) {
  int t = threadIdx.x;
  int ki = blockIdx.x * 32 + (t >> 3);   // 256 blocks x 32 keys
  int part = t & 7;                      // 8 lanes share one key
  float key = s2[ki];
  int rank = 0;
  const float4* p = reinterpret_cast<const float4*>(s2) + part * 256;  // 1024 floats per part
  int jbase = part * 1024;
#pragma unroll 4
  for (int q = 0; q < 256; ++q) {
    float4 v = p[q];
    int j = jbase + q * 4;
    rank += (v.x < key) || (v.x == key && (j + 0) < ki);
    rank += (v.y < key) || (v.y == key && (j + 1) < ki);
    rank += (v.z < key) || (v.z == key && (j + 2) < ki);
    rank += (v.w < key) || (v.w == key && (j + 3) < ki);
  }
  rank += __shfl_xor(rank, 1);
  rank += __shfl_xor(rank, 2);
  rank += __shfl_xor(rank, 4);
  if (part == 0) { s2s[rank] = key; perm[rank] = ki; }
}

// ---- scalar suffix(exp(s2s)) and prefix(exp(a*s2s)) sums + ea/eb tables ----
__global__ __launch_bounds__(1024) void k_scan_scalar(const float* __restrict__ s2s,
                                                      float* __restrict__ sufa,
                                                      float* __restrict__ preb,
                                                      float* __restrict__ eaA,
                                                      float* __restrict__ ebA) {
  __shared__ float pa[1024], pb[1024];
  int t = threadIdx.x;
  float ea[8], eb[8];
  float sa = 0.f, sb = 0.f;
#pragma unroll
  for (int e = 0; e < 8; ++e) {
    float kk = s2s[t * 8 + e];
    ea[e] = expf(kk);
    eb[e] = expf(LRALPHA * kk);
    eaA[t * 8 + e] = ea[e];
    ebA[t * 8 + e] = eb[e];
    sa += ea[e]; sb += eb[e];
  }
  pa[t] = sa; pb[t] = sb;
  __syncthreads();
  for (int off = 1; off < 1024; off <<= 1) {  // Hillis-Steele, pb fwd / pa bwd
    float addb = (t >= off) ? pb[t - off] : 0.f;
    float adda = (t + off < 1024) ? pa[t + off] : 0.f;
    __syncthreads();
    pb[t] += addb; pa[t] += adda;
    __syncthreads();
  }
  float base_b = (t > 0) ? pb[t - 1] : 0.f;       // sum over threads < t
  float base_a = (t < 1023) ? pa[t + 1] : 0.f;    // sum over threads > t
  float run = base_b;
#pragma unroll
  for (int e = 0; e < 8; ++e) { preb[t * 8 + e] = run; run += eb[e]; }
  if (t == 1023) preb[NR] = run;
  run = base_a;
#pragma unroll
  for (int e = 7; e >= 0; --e) { run += ea[e]; sufa[t * 8 + e] = run; }
  if (t == 1023) sufa[NR] = 0.f;
}

// ---- column scans over Wh[perm] with precomputed ea/eb weights ----
__global__ __launch_bounds__(256) void k_passA(const float* __restrict__ Wh,
                                               const float* __restrict__ eaA,
                                               const float* __restrict__ ebA,
                                               const int* __restrict__ perm,
                                               float* __restrict__ chunkA, float* __restrict__ chunkB) {
  int chunk = blockIdx.x;
  int col = blockIdx.y * 256 + threadIdx.x;
  float accA = 0.f, accB = 0.f;
  int r0 = chunk * CHR;
  for (int rl = 0; rl < CHR; ++rl) {
    int r = r0 + rl;
    float v = Wh[(size_t)perm[r] * OUT_F + col];
    accA += eaA[r] * v;
    accB += ebA[r] * v;
  }
  chunkA[chunk * OUT_F + col] = accA;
  chunkB[chunk * OUT_F + col] = accB;
}

__global__ __launch_bounds__(256) void k_passB(const float* __restrict__ chunkA,
                                               const float* __restrict__ chunkB,
                                               float* __restrict__ baseA, float* __restrict__ baseB) {
  int col = blockIdx.x * 256 + threadIdx.x;
  float run = 0.f;
  for (int c = NCH - 1; c >= 0; --c) { baseA[c * OUT_F + col] = run; run += chunkA[c * OUT_F + col]; }
  run = 0.f;
  for (int c = 0; c < NCH; ++c) { baseB[c * OUT_F + col] = run; run += chunkB[c * OUT_F + col]; }
}

__global__ __launch_bounds__(256) void k_passC(const float* __restrict__ Wh,
                                               const float* __restrict__ eaA,
                                               const float* __restrict__ ebA,
                                               const int* __restrict__ perm,
                                               const float* __restrict__ baseA,
                                               const float* __restrict__ baseB,
                                               float* __restrict__ SufA, float* __restrict__ PreB) {
  int chunk = blockIdx.x;
  int col = blockIdx.y * 256 + threadIdx.x;
  int r0 = chunk * CHR;
  float bA = baseA[chunk * OUT_F + col];
  float bB = baseB[chunk * OUT_F + col];
  float acc = 0.f;
  for (int rl = CHR - 1; rl >= 0; --rl) {   // suffix incl.
    int r = r0 + rl;
    float v = Wh[(size_t)perm[r] * OUT_F + col];
    acc += eaA[r] * v;
    SufA[(size_t)r * OUT_F + col] = acc + bA;
  }
  acc = 0.f;
  for (int rl = 0; rl < CHR; ++rl) {        // prefix excl.
    int r = r0 + rl;
    float v = Wh[(size_t)perm[r] * OUT_F + col];
    PreB[(size_t)r * OUT_F + col] = acc + bB;
    acc += ebA[r] * v;
  }
  if (chunk == NCH - 1) {
    SufA[(size_t)NR * OUT_F + col] = 0.f;
    PreB[(size_t)NR * OUT_F + col] = acc + bB;
  }
}

// ---- per-row: binary search threshold rank, combine, elu ----
__global__ __launch_bounds__(256) void k_final(const float* __restrict__ s1,
                                               const float* __restrict__ s2s,
                                               const float* __restrict__ sufa,
                                               const float* __restrict__ preb,
                                               const float* __restrict__ SufA,
                                               const float* __restrict__ PreB,
                                               float* __restrict__ out) {
  int row = blockIdx.x * 4 + (threadIdx.x >> 6);
  int lane = threadIdx.x & 63;
  float sv = s1[row];
  float t = -sv;
  int lo = 0, hi = NR;
  while (lo < hi) {  // first index with s2s[idx] > t
    int mid = (lo + hi) >> 1;
    if (s2s[mid] > t) hi = mid; else lo = mid + 1;
  }
  float E1 = expf(sv), E1a = expf(LRALPHA * sv);
  float Z = E1 * sufa[lo] + E1a * preb[lo];
  const float* rA = SufA + (size_t)lo * OUT_F;
  const float* rB = PreB + (size_t)lo * OUT_F;
#pragma unroll
  for (int e = 0; e < 8; ++e) {
    int kc = e * 64 + lane;
    float num = E1 * rA[kc] + E1a * rB[kc];
    float h = num / Z;
    out[(size_t)row * OUT_F + kc] = (h > 0.f) ? h : expm1f(h);
  }
}

extern "C" void kernel_launch(void* const* d_in, const int* in_sizes, int n_in,
                              void* d_out, int out_size, void* d_ws, size_t ws_size,
                              hipStream_t stream) {
  (void)in_sizes; (void)n_in; (void)out_size; (void)ws_size;
  const float* feat_edge   = (const float*)d_in[0];
  const float* feat_edge_a = (const float*)d_in[1];
  const float* feat_node_a = (const float*)d_in[2];
  const float* weight      = (const float*)d_in[3];
  const float* att         = (const float*)d_in[4];
  float* out = (float*)d_out;

  char* ws = (char*)d_ws;
  size_t off = 0;
  auto alloc = [&](size_t bytes) { size_t o = off; off += (bytes + 255) & ~(size_t)255; return o; };

  float* Wh = (float*)(ws + alloc((size_t)NR * OUT_F * 4));           // 16.78 MB
  // Region hosts B3t (GEMM phase), then SufA+PreB (scan phase) — disjoint lifetimes.
  size_t regionOff = alloc((size_t)(NR + 1) * OUT_F * 4 * 2);          // 33.56 MB
  float* SufA = (float*)(ws + regionOff);
  float* PreB = (float*)(ws + regionOff + (size_t)(NR + 1) * OUT_F * 4);
  short* B3t  = (short*)(ws + regionOff);                              // 1.57 MB

  float* s1   = (float*)(ws + alloc(NR * 4));
  float* s2   = (float*)(ws + alloc(NR * 4));
  float* s2s  = (float*)(ws + alloc(NR * 4));
  int*   perm = (int*)  (ws + alloc(NR * 4));
  float* sufa = (float*)(ws + alloc((NR + 1) * 4));
  float* preb = (float*)(ws + alloc((NR + 1) * 4));
  float* eaA  = (float*)(ws + alloc(NR * 4));
  float* ebA  = (float*)(ws + alloc(NR * 4));
  float* chA  = (float*)(ws + alloc(NCH * OUT_F * 4));
  float* chB  = (float*)(ws + alloc(NCH * OUT_F * 4));
  float* bsA  = (float*)(ws + alloc(NCH * OUT_F * 4));
  float* bsB  = (float*)(ws + alloc(NCH * OUT_F * 4));

  k_dots2<<<(2 * NR) / 4, 256, 0, stream>>>(feat_edge, feat_edge_a, att, s1, s2);
  k_packB<<<(IN_F * OUT_F) / 256, 256, 0, stream>>>(weight, B3t);
  k_gemm<<<dim3(NR / 128, OUT_F / 128), 256, 0, stream>>>(feat_node_a, B3t, Wh);
  k_rank<<<NR / 32, 256, 0, stream>>>(s2, s2s, perm);
  k_scan_scalar<<<1, 1024, 0, stream>>>(s2s, sufa, preb, eaA, ebA);
  k_passA<<<dim3(NCH, 2), 256, 0, stream>>>(Wh, eaA, ebA, perm, chA, chB);
  k_passB<<<2, 256, 0, stream>>>(chA, chB, bsA, bsB);
  k_passC<<<dim3(NCH, 2), 256, 0, stream>>>(Wh, eaA, ebA, perm, bsA, bsB, SufA, PreB);
  k_final<<<NR / 4, 256, 0, stream>>>(s1, s2s, sufa, preb, SufA, PreB, out);
}

// Round 7
// 127.275 us; speedup vs baseline: 1.0850x; 1.0850x over previous
//
#include <hip/hip_runtime.h>
#include <cstdint>
#include <cstddef>

#define LRALPHA 0.1f
static constexpr int NR = 8192;      // N and Na
static constexpr int EF = 256;
static constexpr int IN_F = 512;
static constexpr int OUT_F = 512;
static constexpr int KP2 = 1024;     // fp16 split-2, k'-interleaved [ah,al]
static constexpr int NT = KP2 / 64;  // 16 K'-tiles of 64
static constexpr int NCH = 128;      // chunks for column scans
static constexpr int CHR = 64;       // rows per chunk (NCH*CHR = 8192)

typedef __attribute__((ext_vector_type(8))) _Float16 f16x8;
typedef __attribute__((ext_vector_type(4))) float f32x4;

// ---- fused s1/s2: one wave per row over 16384 virtual rows ----
__global__ __launch_bounds__(256) void k_dots2(const float* __restrict__ feat_edge,
                                               const float* __restrict__ feat_edge_a,
                                               const float* __restrict__ att,
                                               float* __restrict__ s1,
                                               float* __restrict__ s2) {
  int vrow = blockIdx.x * 4 + (threadIdx.x >> 6);
  int lane = threadIdx.x & 63;
  const float* feat; const float* av; float* outp; int row;
  if (vrow < NR) { row = vrow; feat = feat_edge; av = att; outp = s1; }
  else { row = vrow - NR; feat = feat_edge_a; av = att + EF; outp = s2; }
  float4 f = reinterpret_cast<const float4*>(feat + (size_t)row * EF)[lane];
  float4 a = reinterpret_cast<const float4*>(av)[lane];
  float d = f.x * a.x + f.y * a.y + f.z * a.z + f.w * a.w;
#pragma unroll
  for (int off = 32; off > 0; off >>= 1) d += __shfl_xor(d, off);
  if (lane == 0) outp[row] = d;
}

// ---- pack weight TRANSPOSED to fp16, each wh duplicated: B3t[n][2k]=B3t[n][2k+1]=wh ----
__global__ __launch_bounds__(256) void k_packB(const float* __restrict__ W, short* __restrict__ B3t) {
  int i = blockIdx.x * 256 + threadIdx.x;  // < 512*512
  int n = i >> 9, k = i & 511;
  float x = W[(size_t)k * OUT_F + n];
  _Float16 h = (_Float16)x;
  unsigned short u = __builtin_bit_cast(unsigned short, h);
  unsigned int w = (unsigned int)u | ((unsigned int)u << 16);
  *reinterpret_cast<unsigned int*>(B3t + (size_t)n * KP2 + 2 * k) = w;
}

// ---- Wh = split2(A) @ B3t^T : 64x64 tiles, BK'=64, dbuf LDS, reg-staged ----
// fp16 2-term split, k'-interleaved: k'=2k -> ah(k), k'=2k+1 -> al(k); B dup'd.
// 1024 blocks -> 4 blocks/CU: latency hidden by inter-block TLP (m114), not
// by fighting the __syncthreads vmcnt drain (R6 showed that regresses).
struct SReg2 { float4 a0, a1; int4 b0, b1; };

__global__ __launch_bounds__(256, 4) void k_gemm(const float* __restrict__ A,
                                                 const short* __restrict__ B3t,
                                                 float* __restrict__ Wh) {
  // per buffer: [slot=k'/8 (8)][row (64)][8 f16] = 4096 shorts; conflict-free
  // ds_write_b128 (8-lane groups span all 32 banks) and 2-way-free ds_read_b128.
  __shared__ short lA[2][4096];
  __shared__ short lB[2][4096];
  const int tid = threadIdx.x;
  const int wid = tid >> 6, lane = tid & 63;
  const int wr = wid >> 1, wc = wid & 1;
  const int m0 = blockIdx.x * 64, n0 = blockIdx.y * 64;
  const int slot4 = lane >> 4, fr = lane & 15;

  // staging map: row = tid&63, kseg = tid>>6 (8 real k / 16 k' per thread)
  const int srow = tid & 63, kseg = tid >> 6;
  const float* gA = A + (size_t)(m0 + srow) * IN_F + kseg * 8;
  const short* gB = B3t + (size_t)(n0 + srow) * KP2 + kseg * 16;
  const int wOff0 = (2 * kseg) * 512 + srow * 8;   // shorts; cell (slot=2kseg, srow)
  const int wOff1 = wOff0 + 512;                   // cell (slot=2kseg+1, srow)

  f32x4 acc[2][2] = {};

  auto loadR = [&](SReg2& s, int t) {
    const float* pa = gA + t * 32;
    s.a0 = *reinterpret_cast<const float4*>(pa);
    s.a1 = *reinterpret_cast<const float4*>(pa + 4);
    const short* pb = gB + t * 64;
    s.b0 = *reinterpret_cast<const int4*>(pb);
    s.b1 = *reinterpret_cast<const int4*>(pb + 8);
  };

  auto cvt4 = [&](float4 p) -> int4 {  // 4 f32 -> 4 dwords of [ah | al]
    float xs[4] = {p.x, p.y, p.z, p.w};
    int out[4];
#pragma unroll
    for (int e = 0; e < 4; ++e) {
      _Float16 h = (_Float16)xs[e];
      _Float16 l = (_Float16)(xs[e] - (float)h);
      unsigned short uh = __builtin_bit_cast(unsigned short, h);
      unsigned short ul = __builtin_bit_cast(unsigned short, l);
      out[e] = (int)uh | ((int)ul << 16);
    }
    int4 r; r.x = out[0]; r.y = out[1]; r.z = out[2]; r.w = out[3];
    return r;
  };

  auto writeL = [&](int buf, SReg2& s) {
    *reinterpret_cast<int4*>(&lA[buf][wOff0]) = cvt4(s.a0);
    *reinterpret_cast<int4*>(&lA[buf][wOff1]) = cvt4(s.a1);
    *reinterpret_cast<int4*>(&lB[buf][wOff0]) = s.b0;
    *reinterpret_cast<int4*>(&lB[buf][wOff1]) = s.b1;
  };

  auto compute = [&](int buf) {
#pragma unroll
    for (int ks = 0; ks < 2; ++ks) {
      f16x8 af[2], bv[2];
#pragma unroll
      for (int m = 0; m < 2; ++m)
        af[m] = *reinterpret_cast<const f16x8*>(&lA[buf][(ks * 4 + slot4) * 512 + (wr * 32 + m * 16 + fr) * 8]);
#pragma unroll
      for (int n = 0; n < 2; ++n)
        bv[n] = *reinterpret_cast<const f16x8*>(&lB[buf][(ks * 4 + slot4) * 512 + (wc * 32 + n * 16 + fr) * 8]);
#pragma unroll
      for (int m = 0; m < 2; ++m)
#pragma unroll
        for (int n = 0; n < 2; ++n)
          acc[m][n] = __builtin_amdgcn_mfma_f32_16x16x32_f16(af[m], bv[n], acc[m][n], 0, 0, 0);
    }
  };

  SReg2 SA, SB;
  loadR(SA, 0); loadR(SB, 1);
  writeL(0, SA);
  loadR(SA, 2);
  __syncthreads();

  for (int t = 0; t < 12; t += 2) {
    writeL(1, SB); loadR(SB, t + 3);
    compute(0); __syncthreads();
    writeL(0, SA); loadR(SA, t + 4);
    compute(1); __syncthreads();
  }
  // iters 12..15 (stages: SA=14, SB=13)
  writeL(1, SB); loadR(SB, 15);
  compute(0); __syncthreads();
  writeL(0, SA);
  compute(1); __syncthreads();
  writeL(1, SB);
  compute(0); __syncthreads();
  compute(1);

#pragma unroll
  for (int m = 0; m < 2; ++m) {
#pragma unroll
    for (int n = 0; n < 2; ++n) {
      int row = m0 + wr * 32 + m * 16 + slot4 * 4;  // C/D: row=(lane>>4)*4+reg
      int col = n0 + wc * 32 + n * 16 + fr;         //      col=lane&15
#pragma unroll
      for (int r = 0; r < 4; ++r)
        Wh[(size_t)(row + r) * OUT_F + col] = acc[m][n][r];
    }
  }
}

// ---- rank-by-counting: 8 lanes per key, L2-resident reads ----
__global__ __launch_bounds__(256) void k_rank(const float* __restrict__ s2,
                                              float* __restrict__ s2s, int* __restrict__ perm) {
  int t = threadIdx.x;
  int ki = blockIdx.x * 32 + (t >> 3);   // 256 blocks x 32 keys
  int part = t & 7;                      // 8 lanes share one key
  float key = s2[ki];
  int rank = 0;
  const float4* p = reinterpret_cast<const float4*>(s2) + part * 256;  // 1024 floats per part
  int jbase = part * 1024;
#pragma unroll 4
  for (int q = 0; q < 256; ++q) {
    float4 v = p[q];
    int j = jbase + q * 4;
    rank += (v.x < key) || (v.x == key && (j + 0) < ki);
    rank += (v.y < key) || (v.y == key && (j + 1) < ki);
    rank += (v.z < key) || (v.z == key && (j + 2) < ki);
    rank += (v.w < key) || (v.w == key && (j + 3) < ki);
  }
  rank += __shfl_xor(rank, 1);
  rank += __shfl_xor(rank, 2);
  rank += __shfl_xor(rank, 4);
  if (part == 0) { s2s[rank] = key; perm[rank] = ki; }
}

// ---- scalar suffix(exp(s2s)) and prefix(exp(a*s2s)) sums + ea/eb tables ----
__global__ __launch_bounds__(1024) void k_scan_scalar(const float* __restrict__ s2s,
                                                      float* __restrict__ sufa,
                                                      float* __restrict__ preb,
                                                      float* __restrict__ eaA,
                                                      float* __restrict__ ebA) {
  __shared__ float pa[1024], pb[1024];
  int t = threadIdx.x;
  float ea[8], eb[8];
  float sa = 0.f, sb = 0.f;
#pragma unroll
  for (int e = 0; e < 8; ++e) {
    float kk = s2s[t * 8 + e];
    ea[e] = expf(kk);
    eb[e] = expf(LRALPHA * kk);
    eaA[t * 8 + e] = ea[e];
    ebA[t * 8 + e] = eb[e];
    sa += ea[e]; sb += eb[e];
  }
  pa[t] = sa; pb[t] = sb;
  __syncthreads();
  for (int off = 1; off < 1024; off <<= 1) {  // Hillis-Steele, pb fwd / pa bwd
    float addb = (t >= off) ? pb[t - off] : 0.f;
    float adda = (t + off < 1024) ? pa[t + off] : 0.f;
    __syncthreads();
    pb[t] += addb; pa[t] += adda;
    __syncthreads();
  }
  float base_b = (t > 0) ? pb[t - 1] : 0.f;       // sum over threads < t
  float base_a = (t < 1023) ? pa[t + 1] : 0.f;    // sum over threads > t
  float run = base_b;
#pragma unroll
  for (int e = 0; e < 8; ++e) { preb[t * 8 + e] = run; run += eb[e]; }
  if (t == 1023) preb[NR] = run;
  run = base_a;
#pragma unroll
  for (int e = 7; e >= 0; --e) { run += ea[e]; sufa[t * 8 + e] = run; }
  if (t == 1023) sufa[NR] = 0.f;
}

// ---- column scans over Wh[perm] with precomputed ea/eb weights ----
__global__ __launch_bounds__(256) void k_passA(const float* __restrict__ Wh,
                                               const float* __restrict__ eaA,
                                               const float* __restrict__ ebA,
                                               const int* __restrict__ perm,
                                               float* __restrict__ chunkA, float* __restrict__ chunkB) {
  int chunk = blockIdx.x;
  int col = blockIdx.y * 256 + threadIdx.x;
  float accA = 0.f, accB = 0.f;
  int r0 = chunk * CHR;
  for (int rl = 0; rl < CHR; ++rl) {
    int r = r0 + rl;
    float v = Wh[(size_t)perm[r] * OUT_F + col];
    accA += eaA[r] * v;
    accB += ebA[r] * v;
  }
  chunkA[chunk * OUT_F + col] = accA;
  chunkB[chunk * OUT_F + col] = accB;
}

__global__ __launch_bounds__(256) void k_passB(const float* __restrict__ chunkA,
                                               const float* __restrict__ chunkB,
                                               float* __restrict__ baseA, float* __restrict__ baseB) {
  int col = blockIdx.x * 256 + threadIdx.x;
  float run = 0.f;
  for (int c = NCH - 1; c >= 0; --c) { baseA[c * OUT_F + col] = run; run += chunkA[c * OUT_F + col]; }
  run = 0.f;
  for (int c = 0; c < NCH; ++c) { baseB[c * OUT_F + col] = run; run += chunkB[c * OUT_F + col]; }
}

__global__ __launch_bounds__(256) void k_passC(const float* __restrict__ Wh,
                                               const float* __restrict__ eaA,
                                               const float* __restrict__ ebA,
                                               const int* __restrict__ perm,
                                               const float* __restrict__ baseA,
                                               const float* __restrict__ baseB,
                                               float* __restrict__ SufA, float* __restrict__ PreB) {
  int chunk = blockIdx.x;
  int col = blockIdx.y * 256 + threadIdx.x;
  int r0 = chunk * CHR;
  float bA = baseA[chunk * OUT_F + col];
  float bB = baseB[chunk * OUT_F + col];
  float acc = 0.f;
  for (int rl = CHR - 1; rl >= 0; --rl) {   // suffix incl.
    int r = r0 + rl;
    float v = Wh[(size_t)perm[r] * OUT_F + col];
    acc += eaA[r] * v;
    SufA[(size_t)r * OUT_F + col] = acc + bA;
  }
  acc = 0.f;
  for (int rl = 0; rl < CHR; ++rl) {        // prefix excl.
    int r = r0 + rl;
    float v = Wh[(size_t)perm[r] * OUT_F + col];
    PreB[(size_t)r * OUT_F + col] = acc + bB;
    acc += ebA[r] * v;
  }
  if (chunk == NCH - 1) {
    SufA[(size_t)NR * OUT_F + col] = 0.f;
    PreB[(size_t)NR * OUT_F + col] = acc + bB;
  }
}

// ---- per-row: binary search threshold rank, combine, elu ----
__global__ __launch_bounds__(256) void k_final(const float* __restrict__ s1,
                                               const float* __restrict__ s2s,
                                               const float* __restrict__ sufa,
                                               const float* __restrict__ preb,
                                               const float* __restrict__ SufA,
                                               const float* __restrict__ PreB,
                                               float* __restrict__ out) {
  int row = blockIdx.x * 4 + (threadIdx.x >> 6);
  int lane = threadIdx.x & 63;
  float sv = s1[row];
  float t = -sv;
  int lo = 0, hi = NR;
  while (lo < hi) {  // first index with s2s[idx] > t
    int mid = (lo + hi) >> 1;
    if (s2s[mid] > t) hi = mid; else lo = mid + 1;
  }
  float E1 = expf(sv), E1a = expf(LRALPHA * sv);
  float Z = E1 * sufa[lo] + E1a * preb[lo];
  const float* rA = SufA + (size_t)lo * OUT_F;
  const float* rB = PreB + (size_t)lo * OUT_F;
#pragma unroll
  for (int e = 0; e < 8; ++e) {
    int kc = e * 64 + lane;
    float num = E1 * rA[kc] + E1a * rB[kc];
    float h = num / Z;
    out[(size_t)row * OUT_F + kc] = (h > 0.f) ? h : expm1f(h);
  }
}

extern "C" void kernel_launch(void* const* d_in, const int* in_sizes, int n_in,
                              void* d_out, int out_size, void* d_ws, size_t ws_size,
                              hipStream_t stream) {
  (void)in_sizes; (void)n_in; (void)out_size; (void)ws_size;
  const float* feat_edge   = (const float*)d_in[0];
  const float* feat_edge_a = (const float*)d_in[1];
  const float* feat_node_a = (const float*)d_in[2];
  const float* weight      = (const float*)d_in[3];
  const float* att         = (const float*)d_in[4];
  float* out = (float*)d_out;

  char* ws = (char*)d_ws;
  size_t off = 0;
  auto alloc = [&](size_t bytes) { size_t o = off; off += (bytes + 255) & ~(size_t)255; return o; };

  float* Wh = (float*)(ws + alloc((size_t)NR * OUT_F * 4));           // 16.78 MB
  // Region hosts B3t (GEMM phase), then SufA+PreB (scan phase) — disjoint lifetimes.
  size_t regionOff = alloc((size_t)(NR + 1) * OUT_F * 4 * 2);          // 33.56 MB
  float* SufA = (float*)(ws + regionOff);
  float* PreB = (float*)(ws + regionOff + (size_t)(NR + 1) * OUT_F * 4);
  short* B3t  = (short*)(ws + regionOff);                              // 1.05 MB (512x1024 fp16)

  float* s1   = (float*)(ws + alloc(NR * 4));
  float* s2   = (float*)(ws + alloc(NR * 4));
  float* s2s  = (float*)(ws + alloc(NR * 4));
  int*   perm = (int*)  (ws + alloc(NR * 4));
  float* sufa = (float*)(ws + alloc((NR + 1) * 4));
  float* preb = (float*)(ws + alloc((NR + 1) * 4));
  float* eaA  = (float*)(ws + alloc(NR * 4));
  float* ebA  = (float*)(ws + alloc(NR * 4));
  float* chA  = (float*)(ws + alloc(NCH * OUT_F * 4));
  float* chB  = (float*)(ws + alloc(NCH * OUT_F * 4));
  float* bsA  = (float*)(ws + alloc(NCH * OUT_F * 4));
  float* bsB  = (float*)(ws + alloc(NCH * OUT_F * 4));

  k_dots2<<<(2 * NR) / 4, 256, 0, stream>>>(feat_edge, feat_edge_a, att, s1, s2);
  k_packB<<<(IN_F * OUT_F) / 256, 256, 0, stream>>>(weight, B3t);
  k_gemm<<<dim3(NR / 64, OUT_F / 64), 256, 0, stream>>>(feat_node_a, B3t, Wh);
  k_rank<<<NR / 32, 256, 0, stream>>>(s2, s2s, perm);
  k_scan_scalar<<<1, 1024, 0, stream>>>(s2s, sufa, preb, eaA, ebA);
  k_passA<<<dim3(NCH, 2), 256, 0, stream>>>(Wh, eaA, ebA, perm, chA, chB);
  k_passB<<<2, 256, 0, stream>>>(chA, chB, bsA, bsB);
  k_passC<<<dim3(NCH, 2), 256, 0, stream>>>(Wh, eaA, ebA, perm, bsA, bsB, SufA, PreB);
  k_final<<<NR / 4, 256, 0, stream>>>(s1, s2s, sufa, preb, SufA, PreB, out);
}